// Round 2
// 421.822 us; speedup vs baseline: 1.0787x; 1.0787x over previous
//
#include <hip/hip_runtime.h>
#include <math.h>
#include <limits.h>

// FineMatching: one block per m (M=8192), 256 threads.
// v2 (resubmit after infra failure): occupancy push 3 -> 6 blocks/CU.
//  - A-fragments (feat0) loaded direct global->reg (contiguous 8-float rows
//    match the MFMA A layout) -> f0h/f0l LDS (14.3 KB) removed.
//  - ff0/ff1 tails re-read from global in the epilogue (9 lanes x 32 B,
//    L2-resident) -> 5.2 KB removed.
//  LDS 44.5 KB -> 24.7 KB => 6 blocks/CU (__launch_bounds__(256,6), VGPR<=85).
// GEMM on matrix cores via fp16 hi/lo split (3-term MFMA, ~2^-22 accurate).
// d_out (fp32 concat): mkpts0_f[M][2] | mkpts1_f[M][2] | probs[M][9] | sm[M][64][64]

constexpr int TPB = 256;

typedef _Float16 half8_t __attribute__((ext_vector_type(8)));
typedef _Float16 half4_t __attribute__((ext_vector_type(4)));
typedef float    float4_t __attribute__((ext_vector_type(4)));

struct __align__(16) SMem {
    union {
        struct {
            unsigned short f1h[100 * 56];   // 11200 B, 112 B row stride
            unsigned short f1l[100 * 56];   // at +11200 (16B-aligned)
        };
        float sm[64 * 64];                  // 16384 B overlay, valid after GEMM
    };
    float cpart[4][112];
    float csum[112];
    float wval[4];
    int   widx[4];
    float win[9];
};                                          // ~24.7 KB -> 6 blocks/CU

__global__ __launch_bounds__(TPB, 6) void fine_matching_kernel(
    const float* __restrict__ feat0,   // [M][64][64]
    const float* __restrict__ feat1,   // [M][100][64]
    const float* __restrict__ mk0,
    const float* __restrict__ mk1,
    const int* __restrict__ hw0_i,
    const int* __restrict__ hw0_f,
    float* __restrict__ out, int M)
{
    __shared__ SMem S;

    const int m = blockIdx.x;
    const int t = threadIdx.x;
    const int lane = t & 63;
    const int w = t >> 6;        // wave = l-tile (16 rows of l)
    const int col = lane & 15;   // MFMA n-index (r within tile) / A m-index
    const int q = lane >> 4;     // MFMA quad
    const float scale = (float)hw0_i[0] / (float)hw0_f[0];   // 2.0

    const float* g0 = feat0 + (size_t)m * 4096;
    const float* g1 = feat1 + (size_t)m * 6400;
    _Float16* f1h = (_Float16*)S.f1h;
    _Float16* f1l = (_Float16*)S.f1l;

    // ---- A-fragment global loads: row 16w+col, 8 contiguous floats / kstep.
    // Issued before the feat1 staging loop so HBM latency hides under it.
    const int arow = (16 * w + col) * 64;
    float4_t araw[2][2];
    #pragma unroll
    for (int ks = 0; ks < 2; ks++) {
        const int koff = ks ? (32 + q * 8) : (q * 8);
        araw[ks][0] = *(const float4_t*)(g0 + arow + koff);
        araw[ks][1] = *(const float4_t*)(g0 + arow + koff + 4);
    }

    // ---- stage feat1 k<56: global -> hi/lo f16 LDS (c>=56 skipped; those
    // lines are co-fetched with c=48..55 and re-read in the epilogue) ----
    for (int i = t; i < 1600; i += TPB) {
        const int fl = i << 2, l = fl >> 6, c = fl & 63;
        if (c >= 56) continue;
        float4_t v = ((const float4_t*)g1)[i];
        half4_t hi, lo;
        #pragma unroll
        for (int j = 0; j < 4; j++) {
            float x = v[j];
            _Float16 h = (_Float16)x;
            hi[j] = h;
            lo[j] = (_Float16)(x - (float)h);
        }
        *(half4_t*)(f1h + l * 56 + c) = hi;
        *(half4_t*)(f1l + l * 56 + c) = lo;
    }

    // ---- convert A to f16 hi/lo fragments in registers ----
    half8_t hz;
    #pragma unroll
    for (int j = 0; j < 8; j++) hz[j] = (_Float16)0.0f;

    half8_t ah[2], al[2];
    #pragma unroll
    for (int ks = 0; ks < 2; ks++) {
        #pragma unroll
        for (int j = 0; j < 8; j++) {
            float x = araw[ks][j >> 2][j & 3];
            _Float16 h = (_Float16)x;
            ah[ks][j] = h;
            al[ks][j] = (_Float16)(x - (float)h);
        }
    }
    if (q == 3) { ah[1] = hz; al[1] = hz; }   // K padded 56->64: zero pad frags

    __syncthreads();

    // ---- GEMM on MFMA: conf[64][112] = f0[:,:56] @ f1[:,:56]^T / 64 ----
    // wave w owns l in [16w,16w+16); 7 r-tiles of 16. A-frag zeroed for the
    // pad region so B garbage there is harmless.
    float4_t acc[7];
    #pragma unroll
    for (int rt = 0; rt < 7; rt++)
        #pragma unroll
        for (int j = 0; j < 4; j++) acc[rt][j] = 0.0f;

    #pragma unroll
    for (int ks = 0; ks < 2; ks++) {
        const int koff = ks ? (32 + q * 8) : (q * 8);
        const bool kz = (ks == 1) && (q == 3);
        const int bkoff = kz ? 0 : koff;             // safe addr; A-frag is zero
        #pragma unroll
        for (int rt = 0; rt < 7; rt++) {
            int brow = rt * 16 + col;
            if (brow > 99) brow = 99;                // clamp: garbage masked later
            const int bo = brow * 56 + bkoff;
            half8_t bh = *(const half8_t*)(f1h + bo);
            half8_t bl = *(const half8_t*)(f1l + bo);
            acc[rt] = __builtin_amdgcn_mfma_f32_16x16x32_f16(ah[ks], bh, acc[rt], 0, 0, 0);
            acc[rt] = __builtin_amdgcn_mfma_f32_16x16x32_f16(al[ks], bh, acc[rt], 0, 0, 0);
            acc[rt] = __builtin_amdgcn_mfma_f32_16x16x32_f16(ah[ks], bl, acc[rt], 0, 0, 0);
        }
    }

    // C layout: lane holds C[l = 16w + 4q + j][r = 16rt + col], j = 0..3
    // p = exp(conf); no max-subtract (conf O(1), softmax shift-invariant)
    float p[7][4];
    #pragma unroll
    for (int rt = 0; rt < 7; rt++) {
        const bool rvalid = (rt < 6) || (col < 4);   // r < 100
        #pragma unroll
        for (int j = 0; j < 4; j++) {
            float c = acc[rt][j] * (1.0f / 64.0f);
            p[rt][j] = rvalid ? __expf(c) : 0.0f;
        }
    }

    // row sums (over r, per l): lanes sharing l differ only in low-4 bits
    float invr[4];
    #pragma unroll
    for (int j = 0; j < 4; j++) {
        float s = 0.0f;
        #pragma unroll
        for (int rt = 0; rt < 7; rt++) s += p[rt][j];
        s += __shfl_xor(s, 1); s += __shfl_xor(s, 2);
        s += __shfl_xor(s, 4); s += __shfl_xor(s, 8);
        invr[j] = 1.0f / s;
    }

    // col sums (over l, per r): in-thread over j, xor over quads, LDS over waves
    #pragma unroll
    for (int rt = 0; rt < 7; rt++) {
        float s = p[rt][0] + p[rt][1] + p[rt][2] + p[rt][3];
        s += __shfl_xor(s, 16);
        s += __shfl_xor(s, 32);
        if (lane < 16) S.cpart[w][rt * 16 + col] = s;
    }
    __syncthreads();
    if (t < 112)
        S.csum[t] = S.cpart[0][t] + S.cpart[1][t] + S.cpart[2][t] + S.cpart[3][t];
    __syncthreads();    // also: all waves past GEMM -> safe to overlay S.sm on f1

    float invc[7];
    #pragma unroll
    for (int rt = 0; rt < 7; rt++) {
        const bool rvalid = (rt < 6) || (col < 4);
        invc[rt] = rvalid ? 1.0f / S.csum[rt * 16 + col] : 0.0f;
    }

    // ---- sm = p^2/(rsum*csum), crop 10x10 -> 8x8, argmax ----
    float* s_sm = S.sm;
    float bestv = -INFINITY; int besti = INT_MAX;
    #pragma unroll
    for (int j = 0; j < 4; j++) {
        const int l = 16 * w + 4 * q + j;
        #pragma unroll
        for (int rt = 0; rt < 7; rt++) {
            const int r = rt * 16 + col;
            if (r < 100) {
                const int ri = r / 10, rj = r - ri * 10;
                if (ri >= 1 && ri <= 8 && rj >= 1 && rj <= 8) {
                    float pv = p[rt][j];
                    float v = pv * pv * invr[j] * invc[rt];
                    int flat = l * 64 + (ri - 1) * 8 + (rj - 1);
                    s_sm[flat] = v;
                    if (v > bestv) { bestv = v; besti = flat; }  // ascending flat
                }
            }
        }
    }
    #pragma unroll
    for (int d = 1; d < 64; d <<= 1) {               // wave argmax, first-index ties
        float ov = __shfl_xor(bestv, d);
        int   oi = __shfl_xor(besti, d);
        if (ov > bestv || (ov == bestv && oi < besti)) { bestv = ov; besti = oi; }
    }
    if (lane == 0) { S.wval[w] = bestv; S.widx[w] = besti; }
    __syncthreads();

    float bv = S.wval[0]; int best = S.widx[0];
    #pragma unroll
    for (int i = 1; i < 4; i++) {
        float v2 = S.wval[i]; int i2 = S.widx[i];
        if (v2 > bv || (v2 == bv && i2 < best)) { bv = v2; best = i2; }
    }
    const int idx_l = best >> 6;
    const int idx_r = best & 63;
    const int iids  = idx_r >> 3, jids = idx_r & 7;

    // ---- sm -> global (float4) ----
    float* o_sm = out + (size_t)13 * M + (size_t)m * 4096;
    for (int i = t; i < 1024; i += TPB)
        ((float4_t*)o_sm)[i] = ((const float4_t*)s_sm)[i];

    // ---- 3x3 conf_ff window: exact fp32 dots of length 8, tails re-read
    // from global (lines are L2/L3-resident from the staging pass) ----
    if (t < 9) {
        int da = t / 3 - 1, db = t % 3 - 1;
        int wi = iids + da; if (wi < 0) wi += 10;
        int wj = jids + db; if (wj < 0) wj += 10;
        int rp = wi * 10 + wj;
        float4_t a0 = *(const float4_t*)(g0 + idx_l * 64 + 56);
        float4_t a1 = *(const float4_t*)(g0 + idx_l * 64 + 60);
        float4_t b0 = *(const float4_t*)(g1 + rp * 64 + 56);
        float4_t b1 = *(const float4_t*)(g1 + rp * 64 + 60);
        float dot = 0.0f;
        #pragma unroll
        for (int j = 0; j < 4; j++) dot += a0[j] * b0[j] + a1[j] * b1[j];
        S.win[t] = dot * 0.35355339059327373f;       // 1/sqrt(8)
    }
    __syncthreads();

    if (t == 0) {
        float ww[9], mx = -INFINITY;
        #pragma unroll
        for (int i = 0; i < 9; i++) { ww[i] = S.win[i] * 0.1f; mx = fmaxf(mx, ww[i]); }
        float sum = 0.0f;
        #pragma unroll
        for (int i = 0; i < 9; i++) { ww[i] = __expf(ww[i] - mx); sum += ww[i]; }
        float inv = 1.0f / sum;
        float* o_probs = out + (size_t)4 * M + (size_t)m * 9;
        float cx = 0.0f, cy = 0.0f;
        #pragma unroll
        for (int i = 0; i < 9; i++) {
            float pb = ww[i] * inv;
            o_probs[i] = pb;
            cx += pb * (float)(i % 3 - 1);
            cy += pb * (float)(i / 3 - 1);
        }
        float dlx = (float)(idx_l & 7) - 3.5f;
        float dly = (float)(idx_l >> 3) - 3.5f;
        out[2 * m]     = mk0[2 * m]     + dlx * scale;
        out[2 * m + 1] = mk0[2 * m + 1] + dly * scale;
        float drx = (float)jids - 3.5f;
        float dry = (float)iids - 3.5f;
        float* o1 = out + (size_t)2 * M;
        o1[2 * m]     = mk1[2 * m]     + (drx + cx) * scale;
        o1[2 * m + 1] = mk1[2 * m + 1] + (dry + cy) * scale;
    }
}

extern "C" void kernel_launch(void* const* d_in, const int* in_sizes, int n_in,
                              void* d_out, int out_size, void* d_ws, size_t ws_size,
                              hipStream_t stream) {
    const float* feat0 = (const float*)d_in[0];
    const float* feat1 = (const float*)d_in[1];
    const float* mk0   = (const float*)d_in[2];
    const float* mk1   = (const float*)d_in[3];
    const int*   hw0_i = (const int*)d_in[6];
    const int*   hw0_f = (const int*)d_in[7];
    const int M = in_sizes[0] / 4096;

    fine_matching_kernel<<<M, TPB, 0, stream>>>(
        feat0, feat1, mk0, mk1, hw0_i, hw0_f, (float*)d_out, M);
}

// Round 3
// 418.752 us; speedup vs baseline: 1.0866x; 1.0073x over previous
//
#include <hip/hip_runtime.h>
#include <math.h>
#include <limits.h>

// FineMatching: one block per m (M=8192), 256 threads.
// v3: occupancy push 6 -> 7 blocks/CU.
//  - Full LDS overlay: cpart/csum/wval/widx/win moved into the f1 union
//    (they are only live after GEMM; extra barrier added post-GEMM).
//    LDS 25,088 -> 22,528 B => 7 blocks/CU.
//  - Staging loop re-indexed as 700 x 8-element chunks (56 = 7*8): no wasted
//    iterations, ds_write_b128 instead of b64. Per-element math unchanged.
// GEMM on matrix cores via fp16 hi/lo split (3-term MFMA, ~2^-22 accurate).
// d_out (fp32 concat): mkpts0_f[M][2] | mkpts1_f[M][2] | probs[M][9] | sm[M][64][64]

constexpr int TPB = 256;

typedef _Float16 half8_t __attribute__((ext_vector_type(8)));
typedef _Float16 half4_t __attribute__((ext_vector_type(4)));
typedef float    float4_t __attribute__((ext_vector_type(4)));

struct __align__(16) SMem {
    union {
        struct {                            // live: stage + GEMM
            unsigned short f1h[100 * 56];   // 11,200 B, 112 B row stride
            unsigned short f1l[100 * 56];   // at +11,200
        };
        struct {                            // live: post-GEMM (after barrier B2)
            float sm[64 * 64];              // 16,384 B
            float cpart[4][112];            //  1,792 B
            float csum[112];                //    448 B
            float wval[4];
            int   widx[4];
            float win[9];
        };
    };
};                                          // 22,400 B -> 7 blocks/CU

__global__ __launch_bounds__(TPB, 7) void fine_matching_kernel(
    const float* __restrict__ feat0,   // [M][64][64]
    const float* __restrict__ feat1,   // [M][100][64]
    const float* __restrict__ mk0,
    const float* __restrict__ mk1,
    const int* __restrict__ hw0_i,
    const int* __restrict__ hw0_f,
    float* __restrict__ out, int M)
{
    __shared__ SMem S;

    const int m = blockIdx.x;
    const int t = threadIdx.x;
    const int lane = t & 63;
    const int w = t >> 6;        // wave = l-tile (16 rows of l)
    const int col = lane & 15;   // MFMA n-index (r within tile) / A m-index
    const int q = lane >> 4;     // MFMA quad
    const float scale = (float)hw0_i[0] / (float)hw0_f[0];   // 2.0

    const float* g0 = feat0 + (size_t)m * 4096;
    const float* g1 = feat1 + (size_t)m * 6400;
    _Float16* f1h = (_Float16*)S.f1h;
    _Float16* f1l = (_Float16*)S.f1l;

    // ---- A-fragment global loads: row 16w+col, 8 contiguous floats / kstep.
    // Issued before the feat1 staging loop so HBM latency hides under it.
    const int arow = (16 * w + col) * 64;
    float4_t araw[2][2];
    #pragma unroll
    for (int ks = 0; ks < 2; ks++) {
        const int koff = ks ? (32 + q * 8) : (q * 8);
        araw[ks][0] = *(const float4_t*)(g0 + arow + koff);
        araw[ks][1] = *(const float4_t*)(g0 + arow + koff + 4);
    }

    // ---- stage feat1 k<56: 700 chunks of 8 elements (56 = 7*8, no waste).
    // hi/lo f16 split, exact same per-element math as before; b128 LDS writes.
    for (int i = t; i < 700; i += TPB) {
        const int l = i / 7;
        const int c = (i - l * 7) * 8;
        const float* src = g1 + l * 64 + c;
        float4_t v0 = *(const float4_t*)(src);
        float4_t v1 = *(const float4_t*)(src + 4);
        half8_t hi, lo;
        #pragma unroll
        for (int k = 0; k < 4; k++) {
            float x = v0[k];
            _Float16 h = (_Float16)x;
            hi[k] = h;
            lo[k] = (_Float16)(x - (float)h);
        }
        #pragma unroll
        for (int k = 0; k < 4; k++) {
            float x = v1[k];
            _Float16 h = (_Float16)x;
            hi[4 + k] = h;
            lo[4 + k] = (_Float16)(x - (float)h);
        }
        *(half8_t*)(f1h + l * 56 + c) = hi;
        *(half8_t*)(f1l + l * 56 + c) = lo;
    }

    // ---- convert A to f16 hi/lo fragments in registers ----
    half8_t hz;
    #pragma unroll
    for (int j = 0; j < 8; j++) hz[j] = (_Float16)0.0f;

    half8_t ah[2], al[2];
    #pragma unroll
    for (int ks = 0; ks < 2; ks++) {
        #pragma unroll
        for (int j = 0; j < 8; j++) {
            float x = araw[ks][j >> 2][j & 3];
            _Float16 h = (_Float16)x;
            ah[ks][j] = h;
            al[ks][j] = (_Float16)(x - (float)h);
        }
    }
    if (q == 3) { ah[1] = hz; al[1] = hz; }   // K padded 56->64: zero pad frags

    __syncthreads();   // B1: f1 staged

    // ---- GEMM on MFMA: conf[64][112] = f0[:,:56] @ f1[:,:56]^T / 64 ----
    // wave w owns l in [16w,16w+16); 7 r-tiles of 16. A-frag zeroed for the
    // pad region so B garbage there is harmless.
    float4_t acc[7];
    #pragma unroll
    for (int rt = 0; rt < 7; rt++)
        #pragma unroll
        for (int j = 0; j < 4; j++) acc[rt][j] = 0.0f;

    #pragma unroll
    for (int ks = 0; ks < 2; ks++) {
        const int koff = ks ? (32 + q * 8) : (q * 8);
        const bool kz = (ks == 1) && (q == 3);
        const int bkoff = kz ? 0 : koff;             // safe addr; A-frag is zero
        #pragma unroll
        for (int rt = 0; rt < 7; rt++) {
            int brow = rt * 16 + col;
            if (brow > 99) brow = 99;                // clamp: garbage masked later
            const int bo = brow * 56 + bkoff;
            half8_t bh = *(const half8_t*)(f1h + bo);
            half8_t bl = *(const half8_t*)(f1l + bo);
            acc[rt] = __builtin_amdgcn_mfma_f32_16x16x32_f16(ah[ks], bh, acc[rt], 0, 0, 0);
            acc[rt] = __builtin_amdgcn_mfma_f32_16x16x32_f16(al[ks], bh, acc[rt], 0, 0, 0);
            acc[rt] = __builtin_amdgcn_mfma_f32_16x16x32_f16(ah[ks], bl, acc[rt], 0, 0, 0);
        }
    }

    __syncthreads();   // B2: all waves done reading f1 -> overlay region usable

    // C layout: lane holds C[l = 16w + 4q + j][r = 16rt + col], j = 0..3
    // p = exp(conf); no max-subtract (conf O(1), softmax shift-invariant)
    float p[7][4];
    #pragma unroll
    for (int rt = 0; rt < 7; rt++) {
        const bool rvalid = (rt < 6) || (col < 4);   // r < 100
        #pragma unroll
        for (int j = 0; j < 4; j++) {
            float c = acc[rt][j] * (1.0f / 64.0f);
            p[rt][j] = rvalid ? __expf(c) : 0.0f;
        }
    }

    // row sums (over r, per l): lanes sharing l differ only in low-4 bits
    float invr[4];
    #pragma unroll
    for (int j = 0; j < 4; j++) {
        float s = 0.0f;
        #pragma unroll
        for (int rt = 0; rt < 7; rt++) s += p[rt][j];
        s += __shfl_xor(s, 1); s += __shfl_xor(s, 2);
        s += __shfl_xor(s, 4); s += __shfl_xor(s, 8);
        invr[j] = 1.0f / s;
    }

    // col sums (over l, per r): in-thread over j, xor over quads, LDS over waves
    #pragma unroll
    for (int rt = 0; rt < 7; rt++) {
        float s = p[rt][0] + p[rt][1] + p[rt][2] + p[rt][3];
        s += __shfl_xor(s, 16);
        s += __shfl_xor(s, 32);
        if (lane < 16) S.cpart[w][rt * 16 + col] = s;
    }
    __syncthreads();   // B3: cpart complete
    if (t < 112)
        S.csum[t] = S.cpart[0][t] + S.cpart[1][t] + S.cpart[2][t] + S.cpart[3][t];
    __syncthreads();   // B4: csum complete

    float invc[7];
    #pragma unroll
    for (int rt = 0; rt < 7; rt++) {
        const bool rvalid = (rt < 6) || (col < 4);
        invc[rt] = rvalid ? 1.0f / S.csum[rt * 16 + col] : 0.0f;
    }

    // ---- sm = p^2/(rsum*csum), crop 10x10 -> 8x8, argmax ----
    float* s_sm = S.sm;
    float bestv = -INFINITY; int besti = INT_MAX;
    #pragma unroll
    for (int j = 0; j < 4; j++) {
        const int l = 16 * w + 4 * q + j;
        #pragma unroll
        for (int rt = 0; rt < 7; rt++) {
            const int r = rt * 16 + col;
            if (r < 100) {
                const int ri = r / 10, rj = r - ri * 10;
                if (ri >= 1 && ri <= 8 && rj >= 1 && rj <= 8) {
                    float pv = p[rt][j];
                    float v = pv * pv * invr[j] * invc[rt];
                    int flat = l * 64 + (ri - 1) * 8 + (rj - 1);
                    s_sm[flat] = v;
                    if (v > bestv) { bestv = v; besti = flat; }  // ascending flat
                }
            }
        }
    }
    #pragma unroll
    for (int d = 1; d < 64; d <<= 1) {               // wave argmax, first-index ties
        float ov = __shfl_xor(bestv, d);
        int   oi = __shfl_xor(besti, d);
        if (ov > bestv || (ov == bestv && oi < besti)) { bestv = ov; besti = oi; }
    }
    if (lane == 0) { S.wval[w] = bestv; S.widx[w] = besti; }
    __syncthreads();   // B5: sm + wval complete

    float bv = S.wval[0]; int best = S.widx[0];
    #pragma unroll
    for (int i = 1; i < 4; i++) {
        float v2 = S.wval[i]; int i2 = S.widx[i];
        if (v2 > bv || (v2 == bv && i2 < best)) { bv = v2; best = i2; }
    }
    const int idx_l = best >> 6;
    const int idx_r = best & 63;
    const int iids  = idx_r >> 3, jids = idx_r & 7;

    // ---- sm -> global (float4) ----
    float* o_sm = out + (size_t)13 * M + (size_t)m * 4096;
    for (int i = t; i < 1024; i += TPB)
        ((float4_t*)o_sm)[i] = ((const float4_t*)s_sm)[i];

    // ---- 3x3 conf_ff window: exact fp32 dots of length 8, tails re-read
    // from global (lines are L2/L3-resident from the staging pass) ----
    if (t < 9) {
        int da = t / 3 - 1, db = t % 3 - 1;
        int wi = iids + da; if (wi < 0) wi += 10;
        int wj = jids + db; if (wj < 0) wj += 10;
        int rp = wi * 10 + wj;
        float4_t a0 = *(const float4_t*)(g0 + idx_l * 64 + 56);
        float4_t a1 = *(const float4_t*)(g0 + idx_l * 64 + 60);
        float4_t b0 = *(const float4_t*)(g1 + rp * 64 + 56);
        float4_t b1 = *(const float4_t*)(g1 + rp * 64 + 60);
        float dot = 0.0f;
        #pragma unroll
        for (int j = 0; j < 4; j++) dot += a0[j] * b0[j] + a1[j] * b1[j];
        S.win[t] = dot * 0.35355339059327373f;       // 1/sqrt(8)
    }
    __syncthreads();   // B6: win complete

    if (t == 0) {
        float ww[9], mx = -INFINITY;
        #pragma unroll
        for (int i = 0; i < 9; i++) { ww[i] = S.win[i] * 0.1f; mx = fmaxf(mx, ww[i]); }
        float sum = 0.0f;
        #pragma unroll
        for (int i = 0; i < 9; i++) { ww[i] = __expf(ww[i] - mx); sum += ww[i]; }
        float inv = 1.0f / sum;
        float* o_probs = out + (size_t)4 * M + (size_t)m * 9;
        float cx = 0.0f, cy = 0.0f;
        #pragma unroll
        for (int i = 0; i < 9; i++) {
            float pb = ww[i] * inv;
            o_probs[i] = pb;
            cx += pb * (float)(i % 3 - 1);
            cy += pb * (float)(i / 3 - 1);
        }
        float dlx = (float)(idx_l & 7) - 3.5f;
        float dly = (float)(idx_l >> 3) - 3.5f;
        out[2 * m]     = mk0[2 * m]     + dlx * scale;
        out[2 * m + 1] = mk0[2 * m + 1] + dly * scale;
        float drx = (float)jids - 3.5f;
        float dry = (float)iids - 3.5f;
        float* o1 = out + (size_t)2 * M;
        o1[2 * m]     = mk1[2 * m]     + (drx + cx) * scale;
        o1[2 * m + 1] = mk1[2 * m + 1] + (dry + cy) * scale;
    }
}

extern "C" void kernel_launch(void* const* d_in, const int* in_sizes, int n_in,
                              void* d_out, int out_size, void* d_ws, size_t ws_size,
                              hipStream_t stream) {
    const float* feat0 = (const float*)d_in[0];
    const float* feat1 = (const float*)d_in[1];
    const float* mk0   = (const float*)d_in[2];
    const float* mk1   = (const float*)d_in[3];
    const int*   hw0_i = (const int*)d_in[6];
    const int*   hw0_f = (const int*)d_in[7];
    const int M = in_sizes[0] / 4096;

    fine_matching_kernel<<<M, TPB, 0, stream>>>(
        feat0, feat1, mk0, mk1, hw0_i, hw0_f, (float*)d_out, M);
}

// Round 7
// 415.457 us; speedup vs baseline: 1.0952x; 1.0079x over previous
//
#include <hip/hip_runtime.h>
#include <math.h>
#include <limits.h>

// FineMatching: one block per m (M=8192), 256 threads, 7 blocks/CU.
// v4 (3rd resubmit after broker timeouts): critical-path + VALU cuts.
//  - Staging fully unrolled: 3 chunks/thread, all 6 global float4 loads
//    issued up front -> 1 HBM latency instead of 3 serialized.
//  - sm never touches LDS: values kept in regs, argmax from regs, scatter
//    global stores AFTER the last barrier (no vmcnt drain stall).
//  - exp(acc/64) == exp2(acc * fl(log2e)/64): bit-identical, one mul less.
//  - v_rcp_f32 for row/col reciprocals (<=1 ulp, saves ~80 VALU/thread).
//  - mk0/mk1 prefetched at top (kills cold loads in the t==0 tail).
// GEMM on matrix cores via fp16 hi/lo split (3-term MFMA, ~2^-22 accurate).
// d_out (fp32 concat): mkpts0_f[M][2] | mkpts1_f[M][2] | probs[M][9] | sm[M][64][64]

constexpr int TPB = 256;

typedef _Float16 half8_t __attribute__((ext_vector_type(8)));
typedef float    float4_t __attribute__((ext_vector_type(4)));
typedef float    float2_t __attribute__((ext_vector_type(2)));

struct __align__(16) SMem {
    union {
        struct {                            // live: stage + GEMM
            unsigned short f1h[100 * 56];   // 11,200 B, 112 B row stride
            unsigned short f1l[100 * 56];   // at +11,200
        };
        struct {                            // live: post-GEMM (after B2)
            float cpart[4][112];
            float csum[112];
            float wval[4];
            int   widx[4];
            float win[9];
        };
    };
};                                          // 22,400 B -> 7 blocks/CU

__device__ __forceinline__ float fast_rcp(float x) {
#if __has_builtin(__builtin_amdgcn_rcpf)
    return __builtin_amdgcn_rcpf(x);
#else
    return 1.0f / x;
#endif
}

__device__ __forceinline__ float fast_exp2(float x) {
#if __has_builtin(__builtin_amdgcn_exp2f)
    return __builtin_amdgcn_exp2f(x);
#else
    return __expf(x * 0.69314718055994530942f);
#endif
}

__device__ __forceinline__ void split8(float4_t a, float4_t b,
                                       half8_t& hi, half8_t& lo) {
    #pragma unroll
    for (int k = 0; k < 4; k++) {
        float x = a[k]; _Float16 h = (_Float16)x;
        hi[k] = h; lo[k] = (_Float16)(x - (float)h);
    }
    #pragma unroll
    for (int k = 0; k < 4; k++) {
        float x = b[k]; _Float16 h = (_Float16)x;
        hi[4 + k] = h; lo[4 + k] = (_Float16)(x - (float)h);
    }
}

__global__ __launch_bounds__(TPB, 7) void fine_matching_kernel(
    const float* __restrict__ feat0,   // [M][64][64]
    const float* __restrict__ feat1,   // [M][100][64]
    const float* __restrict__ mk0,
    const float* __restrict__ mk1,
    const int* __restrict__ hw0_i,
    const int* __restrict__ hw0_f,
    float* __restrict__ out, int M)
{
    __shared__ SMem S;

    const int m = blockIdx.x;
    const int t = threadIdx.x;
    const int lane = t & 63;
    const int w = t >> 6;        // wave = l-tile (16 rows of l)
    const int col = lane & 15;   // MFMA n-index (r within tile) / A m-index
    const int q = lane >> 4;     // MFMA quad
    const float scale = (float)hw0_i[0] / (float)hw0_f[0];   // 2.0

    const float* g0 = feat0 + (size_t)m * 4096;
    const float* g1 = feat1 + (size_t)m * 6400;
    _Float16* f1h = (_Float16*)S.f1h;
    _Float16* f1l = (_Float16*)S.f1l;

    // epilogue operand prefetch (uniform broadcast loads, consumed at the end)
    const float2_t mkv0 = *(const float2_t*)(mk0 + 2 * m);
    const float2_t mkv1 = *(const float2_t*)(mk1 + 2 * m);

    // ---- staging loads: 700 chunks of 8 (56 = 7*8); thread t owns
    // {t, t+256, t+512 if t<188}. All loads issued before any convert.
    const int c0 = t, c1 = t + 256;
    const bool h2 = (t < 188);                 // t+512 < 700
    const int c2 = h2 ? (t + 512) : t;         // safe addr when inactive
    const int l0g = c0 / 7, k0 = (c0 - l0g * 7) * 8;
    const int l1g = c1 / 7, k1 = (c1 - l1g * 7) * 8;
    const int l2g = c2 / 7, k2 = (c2 - l2g * 7) * 8;
    float4_t u0a = *(const float4_t*)(g1 + l0g * 64 + k0);
    float4_t u0b = *(const float4_t*)(g1 + l0g * 64 + k0 + 4);
    float4_t u1a = *(const float4_t*)(g1 + l1g * 64 + k1);
    float4_t u1b = *(const float4_t*)(g1 + l1g * 64 + k1 + 4);
    float4_t u2a = *(const float4_t*)(g1 + l2g * 64 + k2);
    float4_t u2b = *(const float4_t*)(g1 + l2g * 64 + k2 + 4);

    // ---- A-fragment loads: row 16w+col, 8 contiguous floats / kstep ----
    const int arow = (16 * w + col) * 64;
    float4_t araw[2][2];
    #pragma unroll
    for (int ks = 0; ks < 2; ks++) {
        const int koff = ks ? (32 + q * 8) : (q * 8);
        araw[ks][0] = *(const float4_t*)(g0 + arow + koff);
        araw[ks][1] = *(const float4_t*)(g0 + arow + koff + 4);
    }

    // ---- convert + LDS write staging chunks (per-element math unchanged) ----
    {
        half8_t hi, lo; split8(u0a, u0b, hi, lo);
        *(half8_t*)(f1h + l0g * 56 + k0) = hi;
        *(half8_t*)(f1l + l0g * 56 + k0) = lo;
    }
    {
        half8_t hi, lo; split8(u1a, u1b, hi, lo);
        *(half8_t*)(f1h + l1g * 56 + k1) = hi;
        *(half8_t*)(f1l + l1g * 56 + k1) = lo;
    }
    if (h2) {
        half8_t hi, lo; split8(u2a, u2b, hi, lo);
        *(half8_t*)(f1h + l2g * 56 + k2) = hi;
        *(half8_t*)(f1l + l2g * 56 + k2) = lo;
    }

    // ---- convert A to f16 hi/lo fragments in registers ----
    half8_t hz;
    #pragma unroll
    for (int j = 0; j < 8; j++) hz[j] = (_Float16)0.0f;

    half8_t ah[2], al[2];
    #pragma unroll
    for (int ks = 0; ks < 2; ks++) {
        #pragma unroll
        for (int j = 0; j < 8; j++) {
            float x = araw[ks][j >> 2][j & 3];
            _Float16 h = (_Float16)x;
            ah[ks][j] = h;
            al[ks][j] = (_Float16)(x - (float)h);
        }
    }
    if (q == 3) { ah[1] = hz; al[1] = hz; }   // K padded 56->64: zero pad frags

    __syncthreads();   // B1: f1 staged

    // ---- GEMM on MFMA: conf[64][112] = f0[:,:56] @ f1[:,:56]^T / 64 ----
    float4_t acc[7];
    #pragma unroll
    for (int rt = 0; rt < 7; rt++)
        #pragma unroll
        for (int j = 0; j < 4; j++) acc[rt][j] = 0.0f;

    #pragma unroll
    for (int ks = 0; ks < 2; ks++) {
        const int koff = ks ? (32 + q * 8) : (q * 8);
        const bool kz = (ks == 1) && (q == 3);
        const int bkoff = kz ? 0 : koff;             // safe addr; A-frag is zero
        #pragma unroll
        for (int rt = 0; rt < 7; rt++) {
            int brow = rt * 16 + col;
            if (brow > 99) brow = 99;                // clamp: garbage masked later
            const int bo = brow * 56 + bkoff;
            half8_t bh = *(const half8_t*)(f1h + bo);
            half8_t bl = *(const half8_t*)(f1l + bo);
            acc[rt] = __builtin_amdgcn_mfma_f32_16x16x32_f16(ah[ks], bh, acc[rt], 0, 0, 0);
            acc[rt] = __builtin_amdgcn_mfma_f32_16x16x32_f16(al[ks], bh, acc[rt], 0, 0, 0);
            acc[rt] = __builtin_amdgcn_mfma_f32_16x16x32_f16(ah[ks], bl, acc[rt], 0, 0, 0);
        }
    }

    __syncthreads();   // B2: all waves done reading f1 -> overlay region usable

    // C layout: lane holds C[l = 16w + 4q + j][r = 16rt + col], j = 0..3
    // p = exp(conf) = exp2(acc * log2e/64): /64 exact, single rounding ->
    // bit-identical to exp((acc/64)).  No max-subtract (conf O(1)).
    constexpr float CC = 1.44269504088896340736f / 64.0f;
    float p[7][4];
    #pragma unroll
    for (int rt = 0; rt < 7; rt++) {
        const bool rvalid = (rt < 6) || (col < 4);   // r < 100
        #pragma unroll
        for (int j = 0; j < 4; j++)
            p[rt][j] = rvalid ? fast_exp2(acc[rt][j] * CC) : 0.0f;
    }

    // row sums (over r, per l): lanes sharing l differ only in low-4 bits
    float invr[4];
    #pragma unroll
    for (int j = 0; j < 4; j++) {
        float s = 0.0f;
        #pragma unroll
        for (int rt = 0; rt < 7; rt++) s += p[rt][j];
        s += __shfl_xor(s, 1); s += __shfl_xor(s, 2);
        s += __shfl_xor(s, 4); s += __shfl_xor(s, 8);
        invr[j] = fast_rcp(s);
    }

    // col sums (over l, per r): in-thread over j, xor over quads, LDS over waves
    #pragma unroll
    for (int rt = 0; rt < 7; rt++) {
        float s = p[rt][0] + p[rt][1] + p[rt][2] + p[rt][3];
        s += __shfl_xor(s, 16);
        s += __shfl_xor(s, 32);
        if (lane < 16) S.cpart[w][rt * 16 + col] = s;
    }
    __syncthreads();   // B3: cpart complete
    if (t < 112)
        S.csum[t] = S.cpart[0][t] + S.cpart[1][t] + S.cpart[2][t] + S.cpart[3][t];
    __syncthreads();   // B4: csum complete

    float invc[7];
    #pragma unroll
    for (int rt = 0; rt < 7; rt++) {
        const bool rvalid = (rt < 6) || (col < 4);
        invc[rt] = rvalid ? fast_rcp(S.csum[rt * 16 + col]) : 0.0f;
    }

    // ---- sm = p^2/(rsum*csum) in REGISTERS; crop 10x10 -> 8x8; argmax.
    // Iteration order (j outer, rt inner) visits flat indices ascending per
    // lane -> strict '>' keeps the first max (same ties as reference).
    float v[7][4];
    float bestv = -INFINITY; int besti = INT_MAX;
    #pragma unroll
    for (int j = 0; j < 4; j++) {
        const int l = 16 * w + 4 * q + j;
        #pragma unroll
        for (int rt = 0; rt < 7; rt++) {
            const int r = rt * 16 + col;
            if ((rt < 6) || (col < 4)) {             // r < 100
                const int ri = r / 10, rj = r - ri * 10;
                if (ri >= 1 && ri <= 8 && rj >= 1 && rj <= 8) {
                    float pv = p[rt][j];
                    float val = pv * pv * invr[j] * invc[rt];
                    v[rt][j] = val;
                    int flat = l * 64 + (ri - 1) * 8 + (rj - 1);
                    if (val > bestv) { bestv = val; besti = flat; }
                }
            }
        }
    }
    #pragma unroll
    for (int d = 1; d < 64; d <<= 1) {               // wave argmax, first-index ties
        float ov = __shfl_xor(bestv, d);
        int   oi = __shfl_xor(besti, d);
        if (ov > bestv || (ov == bestv && oi < besti)) { bestv = ov; besti = oi; }
    }
    if (lane == 0) { S.wval[w] = bestv; S.widx[w] = besti; }
    __syncthreads();   // B5: wval complete

    float bv = S.wval[0]; int best = S.widx[0];
    #pragma unroll
    for (int i = 1; i < 4; i++) {
        float v2 = S.wval[i]; int i2 = S.widx[i];
        if (v2 > bv || (v2 == bv && i2 < best)) { bv = v2; best = i2; }
    }
    const int idx_l = best >> 6;
    const int idx_r = best & 63;
    const int iids  = idx_r >> 3, jids = idx_r & 7;

    // ---- 3x3 conf_ff window: exact fp32 dots of length 8, tails re-read
    // from global (lines are L2/L3-resident from the staging pass) ----
    if (t < 9) {
        int da = t / 3 - 1, db = t % 3 - 1;
        int wi = iids + da; if (wi < 0) wi += 10;
        int wj = jids + db; if (wj < 0) wj += 10;
        int rp = wi * 10 + wj;
        float4_t a0 = *(const float4_t*)(g0 + idx_l * 64 + 56);
        float4_t a1 = *(const float4_t*)(g0 + idx_l * 64 + 60);
        float4_t b0 = *(const float4_t*)(g1 + rp * 64 + 56);
        float4_t b1 = *(const float4_t*)(g1 + rp * 64 + 60);
        float dot = 0.0f;
        #pragma unroll
        for (int j = 0; j < 4; j++) dot += a0[j] * b0[j] + a1[j] * b1[j];
        S.win[t] = dot * 0.35355339059327373f;       // 1/sqrt(8)
    }
    __syncthreads();   // B6 (LAST barrier): win complete

    if (t == 0) {
        float ww[9], mx = -INFINITY;
        #pragma unroll
        for (int i = 0; i < 9; i++) { ww[i] = S.win[i] * 0.1f; mx = fmaxf(mx, ww[i]); }
        float sum = 0.0f;
        #pragma unroll
        for (int i = 0; i < 9; i++) { ww[i] = __expf(ww[i] - mx); sum += ww[i]; }
        float inv = 1.0f / sum;
        float* o_probs = out + (size_t)4 * M + (size_t)m * 9;
        float cx = 0.0f, cy = 0.0f;
        #pragma unroll
        for (int i = 0; i < 9; i++) {
            float pb = ww[i] * inv;
            o_probs[i] = pb;
            cx += pb * (float)(i % 3 - 1);
            cy += pb * (float)(i / 3 - 1);
        }
        float dlx = (float)(idx_l & 7) - 3.5f;
        float dly = (float)(idx_l >> 3) - 3.5f;
        out[2 * m]     = mkv0[0] + dlx * scale;
        out[2 * m + 1] = mkv0[1] + dly * scale;
        float drx = (float)jids - 3.5f;
        float dry = (float)iids - 3.5f;
        float* o1 = out + (size_t)2 * M;
        o1[2 * m]     = mkv1[0] + (drx + cx) * scale;
        o1[2 * m + 1] = mkv1[1] + (dry + cy) * scale;
    }

    // ---- sm scatter stores: after the last barrier -> no vmcnt drain stall;
    // retire during block drain. Union of all lanes covers [64][64] exactly. ----
    float* o_sm = out + (size_t)13 * M + (size_t)m * 4096;
    const int lbase = (16 * w + 4 * q) * 64;
    #pragma unroll
    for (int rt = 0; rt < 7; rt++) {
        const int r = rt * 16 + col;
        if ((rt < 6) || (col < 4)) {
            const int ri = r / 10, rj = r - ri * 10;
            if (ri >= 1 && ri <= 8 && rj >= 1 && rj <= 8) {
                const int base = lbase + (ri - 1) * 8 + (rj - 1);
                #pragma unroll
                for (int j = 0; j < 4; j++)
                    o_sm[base + j * 64] = v[rt][j];
            }
        }
    }
}

extern "C" void kernel_launch(void* const* d_in, const int* in_sizes, int n_in,
                              void* d_out, int out_size, void* d_ws, size_t ws_size,
                              hipStream_t stream) {
    const float* feat0 = (const float*)d_in[0];
    const float* feat1 = (const float*)d_in[1];
    const float* mk0   = (const float*)d_in[2];
    const float* mk1   = (const float*)d_in[3];
    const int*   hw0_i = (const int*)d_in[6];
    const int*   hw0_f = (const int*)d_in[7];
    const int M = in_sizes[0] / 4096;

    fine_matching_kernel<<<M, TPB, 0, stream>>>(
        feat0, feat1, mk0, mk1, hw0_i, hw0_f, (float*)d_out, M);
}